// Round 2
// baseline (212.742 us; speedup 1.0000x reference)
//
#include <hip/hip_runtime.h>

// Problem constants
#define CCH   640        // channels
#define WIN   19         // input spatial width
#define NWp   5          // pooled width
#define P     25         // NW*NW
#define BSn   100        // B*S
#define BSC   64000      // BSn*CCH slices per tensor
#define META_ELEMS 3200000
#define SLICE_F 361      // 19*19
#define WGRP_SL 4        // slices per wave (5776 B, 16B-aligned)
#define WGRP_F  (WGRP_SL * SLICE_F)   // 1444 floats
#define WGRP_V4 361      // float4s per wave-group
#define NWG_PER_TENSOR (BSC / WGRP_SL)   // 16000
#define NWG_TOTAL (2 * NWG_PER_TENSOR)   // 32000

typedef float floatx4 __attribute__((ext_vector_type(4)));

// ---------------------------------------------------------------------------
// Kernel 1: adaptive avg pool (UNCHANGED structure — near stream roofline).
// Block 0 additionally zeroes the 100 fan-in counters used by cos_fused
// (stream order guarantees visibility at the kernel boundary).
// ---------------------------------------------------------------------------
__global__ __launch_bounds__(256) void pool_kernel(
    const float* __restrict__ sup, const float* __restrict__ qry,
    float* __restrict__ out, int* __restrict__ cnt) {
  if (blockIdx.x == 0 && threadIdx.x < BSn) cnt[threadIdx.x] = 0;

  __shared__ __align__(16) float tile[4][WGRP_F];   // 23104 B, wave-private quarters
  const int lane = threadIdx.x & 63;
  const int wave = threadIdx.x >> 6;
  const int wg = blockIdx.x * 4 + wave;             // [0, 32000)
  const int which = (wg >= NWG_PER_TENSOR) ? 1 : 0;
  const int g = which ? wg - NWG_PER_TENSOR : wg;
  const float* __restrict__ src = (which ? qry : sup) + (size_t)g * WGRP_F;
  float* __restrict__ lt = &tile[wave][0];

  // Stage 1444 floats: 6 nontemporal float4 loads per lane (last partial).
  floatx4 v[6];
#pragma unroll
  for (int i = 0; i < 6; ++i) {
    const int idx = i * 64 + lane;
    if (idx < WGRP_V4)
      v[i] = __builtin_nontemporal_load((const floatx4*)src + idx);
  }
#pragma unroll
  for (int i = 0; i < 6; ++i) {
    const int idx = i * 64 + lane;
    if (idx < WGRP_V4) *(floatx4*)(lt + idx * 4) = v[i];
  }

  // Pool: 100 outputs per wave-group.
  const int slice0 = g * WGRP_SL;
  for (int o = lane; o < WGRP_SL * P; o += 64) {
    const int s = o / P, p = o - s * P;
    const int i = p / NWp, j = p - i * NWp;
    const int r0 = (i * WIN) / NWp, r1 = ((i + 1) * WIN + NWp - 1) / NWp;
    const int c0 = (j * WIN) / NWp, c1 = ((j + 1) * WIN + NWp - 1) / NWp;
    const float* __restrict__ tb = lt + s * SLICE_F;
    float sum = 0.f;
    for (int r = r0; r < r1; ++r)
#pragma unroll
      for (int c = 0; c < 5; ++c) {                 // max bin width is 5
        if (c0 + c < c1) sum += tb[r * WIN + c0 + c];
      }
    const float val = sum / (float)((r1 - r0) * (c1 - c0));
    const int rem = slice0 + s;
    const int bs = rem / CCH, cch = rem - bs * CCH;
    out[((size_t)bs * (2 * CCH) + which * CCH + cch) * P + p] = val;
  }
}

// ---------------------------------------------------------------------------
// Kernel 2 (fused): partial dots/norms per (bs, 128-ch chunk), 500 blocks,
// then last-arriving block per bs performs the final reduce+normalize+max.
// Fan-in: release fence + atomicAdd on cnt[bs]; 5th arriver acquires and
// finishes. Finale reads of cross-block partials are volatile (sc0/sc1 —
// bypass potentially-stale L1/L2 lines across XCDs).
// ---------------------------------------------------------------------------
#define CHUNK 128
#define ROWS  132                         // CHUNK + 4 pad
__global__ __launch_bounds__(640) void cos_fused(
    const float* __restrict__ meta, float* __restrict__ dpart,
    float* __restrict__ spart, float* __restrict__ qpart,
    int* __restrict__ cnt, float* __restrict__ out) {
  __shared__ __align__(16) float ls[P * ROWS];
  __shared__ __align__(16) float lq[P * ROWS];
  __shared__ int lastflag;
  const int t = threadIdx.x;
  const int blk = blockIdx.x;              // bs*5 + ch
  const int bs = blk / 5, ch = blk - bs * 5;
  const float* __restrict__ sb = meta + (size_t)bs * (2 * CCH * P) + ch * (CHUNK * P);
  const float* __restrict__ qb = sb + CCH * P;

  // Stage [c][p] -> LDS [p][c] via float4 global loads (3200 floats = 800 f4,
  // both bases 16B-aligned), scalar transpose-scatter into padded rows.
  for (int idx = t; idx < (CHUNK * P) / 4; idx += 640) {
    const floatx4 vs = ((const floatx4*)sb)[idx];
    const floatx4 vq = ((const floatx4*)qb)[idx];
#pragma unroll
    for (int e = 0; e < 4; ++e) {
      const int f = idx * 4 + e;
      const int c = f / P, p = f - c * P;
      ls[p * ROWS + c] = vs[e];
      lq[p * ROWS + c] = vq[e];
    }
  }
  __syncthreads();

  if (t < P * P) {
    const int p = t / P, q = t - p * P;
    const floatx4* __restrict__ ap = (const floatx4*)(ls + p * ROWS);
    const floatx4* __restrict__ bq = (const floatx4*)(lq + q * ROWS);
    floatx4 acc = {0.f, 0.f, 0.f, 0.f};
#pragma unroll 8
    for (int k = 0; k < CHUNK / 4; ++k) {
      const floatx4 a = ap[k], b = bq[k];
      acc.x = fmaf(a.x, b.x, acc.x);
      acc.y = fmaf(a.y, b.y, acc.y);
      acc.z = fmaf(a.z, b.z, acc.z);
      acc.w = fmaf(a.w, b.w, acc.w);
    }
    dpart[(size_t)blk * (P * P) + t] = (acc.x + acc.y) + (acc.z + acc.w);
  }
  if (t < P) {
    const floatx4* __restrict__ ap = (const floatx4*)(ls + t * ROWS);
    floatx4 acc = {0.f, 0.f, 0.f, 0.f};
#pragma unroll 8
    for (int k = 0; k < CHUNK / 4; ++k) {
      const floatx4 a = ap[k];
      acc.x = fmaf(a.x, a.x, acc.x);
      acc.y = fmaf(a.y, a.y, acc.y);
      acc.z = fmaf(a.z, a.z, acc.z);
      acc.w = fmaf(a.w, a.w, acc.w);
    }
    spart[blk * P + t] = (acc.x + acc.y) + (acc.z + acc.w);
  } else if (t >= 32 && t < 32 + P) {
    const int q = t - 32;
    const floatx4* __restrict__ bq = (const floatx4*)(lq + q * ROWS);
    floatx4 acc = {0.f, 0.f, 0.f, 0.f};
#pragma unroll 8
    for (int k = 0; k < CHUNK / 4; ++k) {
      const floatx4 b = bq[k];
      acc.x = fmaf(b.x, b.x, acc.x);
      acc.y = fmaf(b.y, b.y, acc.y);
      acc.z = fmaf(b.z, b.z, acc.z);
      acc.w = fmaf(b.w, b.w, acc.w);
    }
    qpart[blk * P + q] = (acc.x + acc.y) + (acc.z + acc.w);
  }

  // ---- fan-in: last block of the 5 chunks for this bs does the finale ----
  __syncthreads();                         // vmcnt drained: partial stores issued
  if (t == 0) {
    __threadfence();                       // device-scope release
    const int v = atomicAdd(&cnt[bs], 1);
    lastflag = (v == 4);
    if (v == 4) __threadfence();           // device-scope acquire
  }
  __syncthreads();
  if (!lastflag) return;

  // Final reduce for this bs (only one block per bs reaches here).
  // Volatile global reads -> fresh data regardless of cache state.
  volatile const float* vdp = dpart;
  volatile const float* vsp = spart;
  volatile const float* vqp = qpart;
  float* sn = ls;            // reuse LDS
  float* qn = ls + 32;
  float* simbuf = lq;
  if (t < P) {
    float a = 0.f;
#pragma unroll
    for (int c5 = 0; c5 < 5; ++c5) a += vsp[(bs * 5 + c5) * P + t];
    sn[t] = sqrtf(a);
  } else if (t >= 32 && t < 32 + P) {
    const int q = t - 32;
    float a = 0.f;
#pragma unroll
    for (int c5 = 0; c5 < 5; ++c5) a += vqp[(bs * 5 + c5) * P + q];
    qn[q] = sqrtf(a);
  }
  __syncthreads();
  if (t < P * P) {
    const int p = t / P, q = t - p * P;
    float d = 0.f;
#pragma unroll
    for (int c5 = 0; c5 < 5; ++c5)
      d += vdp[(size_t)(bs * 5 + c5) * (P * P) + t];
    simbuf[t] = d / fmaxf(sn[p] * qn[q], 1e-8f);
  }
  __syncthreads();
  if (t < P) {
    float m = simbuf[t * P];
#pragma unroll
    for (int k = 1; k < P; ++k) m = fmaxf(m, simbuf[t * P + k]);
    out[META_ELEMS + bs * P + t] = m;
  }
}

extern "C" void kernel_launch(void* const* d_in, const int* in_sizes, int n_in,
                              void* d_out, int out_size, void* d_ws, size_t ws_size,
                              hipStream_t stream) {
  const float* sup = (const float*)d_in[0];
  const float* qry = (const float*)d_in[1];
  float* out = (float*)d_out;

  // Workspace (floats): dpart[500*625], spart[500*25], qpart[500*25], cnt[100]
  float* dpart = (float*)d_ws;
  float* spart = dpart + 500 * (P * P);
  float* qpart = spart + 500 * P;
  int* cnt = (int*)(qpart + 500 * P);

  pool_kernel<<<NWG_TOTAL / 4, 256, 0, stream>>>(sup, qry, out, cnt);
  cos_fused<<<BSn * 5, 640, 0, stream>>>(out, dpart, spart, qpart, cnt, out);
}

// Round 3
// 196.563 us; speedup vs baseline: 1.0823x; 1.0823x over previous
//
#include <hip/hip_runtime.h>

// Problem constants
#define CCH   640        // channels
#define WIN   19         // input spatial width
#define NWp   5          // pooled width
#define P     25         // NW*NW
#define BSn   100        // B*S
#define BSC   64000      // BSn*CCH slices per tensor
#define META_ELEMS 3200000
#define SLICE_F 361      // 19*19
#define WGRP_SL 4        // slices per wave (5776 B, 16B-aligned)
#define WGRP_F  (WGRP_SL * SLICE_F)   // 1444 floats
#define WGRP_V4 361      // float4s per wave-group
#define NWG_PER_TENSOR (BSC / WGRP_SL)   // 16000
#define NWG_TOTAL (2 * NWG_PER_TENSOR)   // 32000

typedef float floatx4 __attribute__((ext_vector_type(4)));

// ---------------------------------------------------------------------------
// Kernel 1: adaptive avg pool. Wave-autonomous: each wave stages its private
// 4-slice group via NONTEMPORAL float4 loads -> LDS -> pool -> coalesced
// store. No barriers; LDS region is wave-private. (Verified 197.5 µs config.)
// ---------------------------------------------------------------------------
__global__ __launch_bounds__(256) void pool_kernel(
    const float* __restrict__ sup, const float* __restrict__ qry,
    float* __restrict__ out) {
  __shared__ __align__(16) float tile[4][WGRP_F];   // 23104 B, wave-private quarters
  const int lane = threadIdx.x & 63;
  const int wave = threadIdx.x >> 6;
  const int wg = blockIdx.x * 4 + wave;             // [0, 32000)
  const int which = (wg >= NWG_PER_TENSOR) ? 1 : 0;
  const int g = which ? wg - NWG_PER_TENSOR : wg;
  const float* __restrict__ src = (which ? qry : sup) + (size_t)g * WGRP_F;
  float* __restrict__ lt = &tile[wave][0];

  // Stage 1444 floats: 6 nontemporal float4 loads per lane (last partial).
  floatx4 v[6];
#pragma unroll
  for (int i = 0; i < 6; ++i) {
    const int idx = i * 64 + lane;
    if (idx < WGRP_V4)
      v[i] = __builtin_nontemporal_load((const floatx4*)src + idx);
  }
#pragma unroll
  for (int i = 0; i < 6; ++i) {
    const int idx = i * 64 + lane;
    if (idx < WGRP_V4) *(floatx4*)(lt + idx * 4) = v[i];
  }

  // Pool: 100 outputs per wave-group.
  const int slice0 = g * WGRP_SL;
  for (int o = lane; o < WGRP_SL * P; o += 64) {
    const int s = o / P, p = o - s * P;
    const int i = p / NWp, j = p - i * NWp;
    const int r0 = (i * WIN) / NWp, r1 = ((i + 1) * WIN + NWp - 1) / NWp;
    const int c0 = (j * WIN) / NWp, c1 = ((j + 1) * WIN + NWp - 1) / NWp;
    const float* __restrict__ tb = lt + s * SLICE_F;
    float sum = 0.f;
    for (int r = r0; r < r1; ++r)
#pragma unroll
      for (int c = 0; c < 5; ++c) {                 // max bin width is 5
        if (c0 + c < c1) sum += tb[r * WIN + c0 + c];
      }
    const float val = sum / (float)((r1 - r0) * (c1 - c0));
    const int rem = slice0 + s;
    const int bs = rem / CCH, cch = rem - bs * CCH;
    out[((size_t)bs * (2 * CCH) + which * CCH + cch) * P + p] = val;
  }
}

// ---------------------------------------------------------------------------
// Kernel 2a: partial dots/norms per (bs, 128-channel chunk). 500 blocks.
// Transposed padded LDS layout [p][c] (row stride 132 floats, 16B-aligned)
// so the dot loop uses float4 LDS reads. Staging now uses float4 GLOBAL
// loads (3200 floats = 800 f4 per tensor chunk; both bases 16B-aligned)
// with a scalar transpose-scatter into LDS — 4x fewer global load instrs
// than the scalar-load version. (Only change vs the 197.5 µs baseline.)
// ---------------------------------------------------------------------------
#define CHUNK 128
#define ROWS  132                         // CHUNK + 4 pad
__global__ __launch_bounds__(640) void cos_part(
    const float* __restrict__ meta, float* __restrict__ dpart,
    float* __restrict__ spart, float* __restrict__ qpart) {
  __shared__ __align__(16) float ls[P * ROWS];
  __shared__ __align__(16) float lq[P * ROWS];
  const int t = threadIdx.x;
  const int blk = blockIdx.x;              // bs*5 + ch
  const int bs = blk / 5, ch = blk - bs * 5;
  const float* __restrict__ sb = meta + (size_t)bs * (2 * CCH * P) + ch * (CHUNK * P);
  const float* __restrict__ qb = sb + CCH * P;

  for (int idx = t; idx < (CHUNK * P) / 4; idx += 640) {
    const floatx4 vs = ((const floatx4*)sb)[idx];
    const floatx4 vq = ((const floatx4*)qb)[idx];
#pragma unroll
    for (int e = 0; e < 4; ++e) {
      const int f = idx * 4 + e;
      const int c = f / P, p = f - c * P;
      ls[p * ROWS + c] = vs[e];
      lq[p * ROWS + c] = vq[e];
    }
  }
  __syncthreads();

  if (t < P * P) {
    const int p = t / P, q = t - p * P;
    const floatx4* __restrict__ ap = (const floatx4*)(ls + p * ROWS);
    const floatx4* __restrict__ bq = (const floatx4*)(lq + q * ROWS);
    floatx4 acc = {0.f, 0.f, 0.f, 0.f};
#pragma unroll 8
    for (int k = 0; k < CHUNK / 4; ++k) {
      const floatx4 a = ap[k], b = bq[k];
      acc.x = fmaf(a.x, b.x, acc.x);
      acc.y = fmaf(a.y, b.y, acc.y);
      acc.z = fmaf(a.z, b.z, acc.z);
      acc.w = fmaf(a.w, b.w, acc.w);
    }
    dpart[(size_t)blk * (P * P) + t] = (acc.x + acc.y) + (acc.z + acc.w);
  }
  if (t < P) {
    const floatx4* __restrict__ ap = (const floatx4*)(ls + t * ROWS);
    floatx4 acc = {0.f, 0.f, 0.f, 0.f};
#pragma unroll 8
    for (int k = 0; k < CHUNK / 4; ++k) {
      const floatx4 a = ap[k];
      acc.x = fmaf(a.x, a.x, acc.x);
      acc.y = fmaf(a.y, a.y, acc.y);
      acc.z = fmaf(a.z, a.z, acc.z);
      acc.w = fmaf(a.w, a.w, acc.w);
    }
    spart[blk * P + t] = (acc.x + acc.y) + (acc.z + acc.w);
  } else if (t >= 32 && t < 32 + P) {
    const int q = t - 32;
    const floatx4* __restrict__ bq = (const floatx4*)(lq + q * ROWS);
    floatx4 acc = {0.f, 0.f, 0.f, 0.f};
#pragma unroll 8
    for (int k = 0; k < CHUNK / 4; ++k) {
      const floatx4 b = bq[k];
      acc.x = fmaf(b.x, b.x, acc.x);
      acc.y = fmaf(b.y, b.y, acc.y);
      acc.z = fmaf(b.z, b.z, acc.z);
      acc.w = fmaf(b.w, b.w, acc.w);
    }
    qpart[blk * P + q] = (acc.x + acc.y) + (acc.z + acc.w);
  }
}

// ---------------------------------------------------------------------------
// Kernel 2b: reduce 5 partials, normalize, max over query positions.
// ---------------------------------------------------------------------------
__global__ __launch_bounds__(640) void cos_final(
    const float* __restrict__ dpart, const float* __restrict__ spart,
    const float* __restrict__ qpart, float* __restrict__ out) {
  __shared__ float sn[P], qn[P], simbuf[P * P];
  const int t = threadIdx.x, bs = blockIdx.x;
  if (t < P) {
    float a = 0.f;
#pragma unroll
    for (int ch = 0; ch < 5; ++ch) a += spart[(bs * 5 + ch) * P + t];
    sn[t] = sqrtf(a);
  } else if (t >= 32 && t < 32 + P) {
    const int q = t - 32;
    float a = 0.f;
#pragma unroll
    for (int ch = 0; ch < 5; ++ch) a += qpart[(bs * 5 + ch) * P + q];
    qn[q] = sqrtf(a);
  }
  __syncthreads();
  if (t < P * P) {
    const int p = t / P, q = t - p * P;
    float d = 0.f;
#pragma unroll
    for (int ch = 0; ch < 5; ++ch) d += dpart[(size_t)(bs * 5 + ch) * (P * P) + t];
    simbuf[t] = d / fmaxf(sn[p] * qn[q], 1e-8f);
  }
  __syncthreads();
  if (t < P) {
    float m = simbuf[t * P];
#pragma unroll
    for (int k = 1; k < P; ++k) m = fmaxf(m, simbuf[t * P + k]);
    out[META_ELEMS + bs * P + t] = m;
  }
}

extern "C" void kernel_launch(void* const* d_in, const int* in_sizes, int n_in,
                              void* d_out, int out_size, void* d_ws, size_t ws_size,
                              hipStream_t stream) {
  const float* sup = (const float*)d_in[0];
  const float* qry = (const float*)d_in[1];
  float* out = (float*)d_out;

  // Workspace (floats): dpart[500*625], spart[500*25], qpart[500*25]
  float* dpart = (float*)d_ws;
  float* spart = dpart + 500 * (P * P);
  float* qpart = spart + 500 * P;

  pool_kernel<<<NWG_TOTAL / 4, 256, 0, stream>>>(sup, qry, out);
  cos_part<<<BSn * 5, 640, 0, stream>>>(out, dpart, spart, qpart);
  cos_final<<<BSn, 640, 0, stream>>>(dpart, spart, qpart, out);
}